// Round 9
// baseline (238.788 us; speedup 1.0000x reference)
//
#include <hip/hip_runtime.h>
#include <math.h>

#define SRC_H 480
#define SRC_W 640
#define RES_H 384
#define RES_W 512
#define NT 16
#define NPIX (RES_H * RES_W)        /* 196608 */
#define PLANE (SRC_H * SRC_W)       /* 307200 */
#define NCH 30                      /* chunks per plane */
#define SCALE_X (639.0f / 511.0f)
#define SCALE_Y (479.0f / 383.0f)

typedef float f32x4 __attribute__((ext_vector_type(4)));
typedef float f32x2 __attribute__((ext_vector_type(2)));

/* output layout (floats, concatenated in return order) */
#define O_SPARSE 0
#define N_SPARSE (NT * 96 * 128 * 2)
#define O_XY (O_SPARSE + N_SPARSE)
#define N_XY (NT * NPIX * 2)
#define O_Z (O_XY + N_XY)
#define N_Z (NT * NPIX)
#define O_VIS (O_Z + N_Z)
#define O_TRAJ (O_VIS + N_Z)

/* ---- helpers ---- */

__device__ inline f32x4 ld4u(const float* p) {
    f32x4 v; __builtin_memcpy(&v, p, 16); return v;
}

__device__ inline float ay_weight(int i) {
    const float s = 479.0f / 383.0f;
    float acc = 0.f;
    int lo = (int)floorf((float)(i - 1) / s) - 2; if (lo < 0) lo = 0;
    int hi = (int)ceilf((float)(i + 1) / s) + 2; if (hi > RES_H - 1) hi = RES_H - 1;
    for (int oy = lo; oy <= hi; ++oy) {
        float ys = (float)oy * s;
        int y0 = (int)floorf(ys);
        float wy = ys - (float)y0;
        int y1 = min(y0 + 1, SRC_H - 1);
        if (y0 == i) acc += (1.f - wy);
        if (y1 == i) acc += wy;
    }
    return acc * (1.0f / RES_H);
}

__device__ inline float ax_weight(int xs) {
    const float s2 = 639.0f / 511.0f;
    float acc = 0.f;
    int lo = (int)floorf((float)(xs - 1) / s2) - 2; if (lo < 0) lo = 0;
    int hi = (int)ceilf((float)(xs + 1) / s2) + 2; if (hi > RES_W - 1) hi = RES_W - 1;
    for (int ox = lo; ox <= hi; ++ox) {
        float xv = (float)ox * s2;
        int x0 = (int)floorf(xv);
        float wx = xv - (float)x0;
        int x1 = min(x0 + 1, SRC_W - 1);
        if (x0 == xs) acc += (1.f - wx);
        if (x1 == xs) acc += wx;
    }
    return acc * (1.0f / RES_W);
}

__device__ inline float pxchain(float v) {
    float a = v / 640.f; float b = 2.f * (a - 0.5f); float c = b + 1.f;
    float p = (c * 0.5f) * 639.f;
    return fminf(fmaxf(p, 0.f), 639.f);
}
__device__ inline float pychain(float v) {
    float a = v / 480.f; float b = 2.f * (a - 0.5f); float c = b + 1.f;
    float p = (c * 0.5f) * 479.f;
    return fminf(fmaxf(p, 0.f), 479.f);
}

__device__ inline f32x4 vrow(const float* rp, bool c1, bool c2, bool c3,
                             float w0, float w1, float w2, float w3) {
    f32x4 A = ld4u(rp), B = ld4u(rp + 4);
    float q0 = A.x, q1 = A.y, q2 = A.z, q3 = A.w, q4 = B.x, q5 = B.y;
    float u0 = q0,            t0 = q1;
    float u1 = c1 ? q2 : q1,  t1 = c1 ? q3 : q2;
    float u2 = c2 ? q3 : q2,  t2 = c2 ? q4 : q3;
    float u3 = c3 ? q4 : q3,  t3 = c3 ? q5 : q4;
    return (f32x4){u0 * (1.f - w0) + t0 * w0, u1 * (1.f - w1) + t1 * w1,
                   u2 * (1.f - w2) + t2 * w2, u3 * (1.f - w3) + t3 * w3};
}

/* one feat reduction unit: plane (0..47), chunk (0..29) -> tree-reduced double */
__device__ inline double feat_unit(const float* __restrict__ video,
                                   const float* axs, const float* ays,
                                   int plane, int chunk, int tid, double* sh) {
    const f32x4* v = (const f32x4*)(video + (size_t)plane * PLANE + (size_t)chunk * 10240);
    double s = 0.0;
#pragma unroll
    for (int it = 0; it < 10; ++it) {
        int idx = it * 256 + tid;
        f32x4 q = v[idx];
        int row = idx / 160;
        int xq = (idx - row * 160) * 4;
        float w = ays[row];
        s += (double)(w * axs[xq + 0]) * (double)q.x
           + (double)(w * axs[xq + 1]) * (double)q.y
           + (double)(w * axs[xq + 2]) * (double)q.z
           + (double)(w * axs[xq + 3]) * (double)q.w;
    }
    sh[tid] = s;
    __syncthreads();
    for (int off = 128; off > 0; off >>= 1) {
        if (tid < off) sh[tid] += sh[tid + off];
        __syncthreads();
    }
    return sh[0];
}

/* one output tile = 1024 px = 2 rows of frame t */
__device__ inline void process_tile(const float* __restrict__ video,
                                    const float* __restrict__ depth,
                                    float dx, float dy, float fmt,
                                    int t, int blk, int tid,
                                    float* ls, float* __restrict__ out) {
    int lp0 = tid * 4;
    int y = blk * 2 + (tid >> 7);
    int x0 = (tid & 127) << 2;
    float tf = (float)t;

    float tyv = fminf(fmaxf((float)y + tf * dy, 0.f), 383.f);
    int y0 = (int)floorf(tyv);
    int y1 = min(y0 + 1, RES_H - 1);
    float wy = tyv - (float)y0;
    const float* dep = depth + (size_t)t * PLANE;
    int dro0 = (y0 + (y0 >> 2)) * SRC_W;
    int dro1 = (y1 + (y1 >> 2)) * SRC_W;
    float ytrk_c = tyv * SCALE_Y;

    const float* vt = video + (size_t)t * 3 * PLANE;

    float xt[4], yt[4], dv[4], vv[4], X4[4], Y4[4], col0[4], col1[4], col2[4];

    float tdx = tf * dx;
    float t0f = (float)x0 + tdx;
    int X = (int)floorf(t0f);
    float xtrk0 = t0f * SCALE_X;
    float px0 = pxchain(xtrk0);
    int CS = (int)floorf(px0);
    bool vecok = (x0 <= 504) && (t0f >= 0.f) && (t0f + 3.f <= 511.f)
              && (X <= 506) && (CS <= 632);

    if (vecok) {
        float wxu = t0f - (float)X;
        int s0 = X + (X >> 2);
        int bq = X & 3;
        bool d1 = (bq == 3), d2 = (bq >= 2), d3 = (bq >= 1);
        {
            f32x4 Da = ld4u(dep + dro0 + s0), Db = ld4u(dep + dro0 + s0 + 4);
            f32x4 Ea = ld4u(dep + dro1 + s0), Eb = ld4u(dep + dro1 + s0 + 4);
            float a0 = Da.x, a1 = Da.y, a2 = Da.z, a3 = Da.w, a4 = Db.x, a5 = Db.y;
            float v0 = a0, v1 = d1 ? a2 : a1, v2 = d2 ? a3 : a2, v3 = d3 ? a4 : a3, v4 = a5;
            float g0 = Ea.x, g1 = Ea.y, g2 = Ea.z, g3 = Ea.w, g4 = Eb.x, g5 = Eb.y;
            float h0 = g0, h1 = d1 ? g2 : g1, h2 = d2 ? g3 : g2, h3 = d3 ? g4 : g3, h4 = g5;
            float iw = 1.f - wxu;
            float r00 = v0 * iw + v1 * wxu, r01 = v1 * iw + v2 * wxu;
            float r02 = v2 * iw + v3 * wxu, r03 = v3 * iw + v4 * wxu;
            float r10 = h0 * iw + h1 * wxu, r11 = h1 * iw + h2 * wxu;
            float r12 = h2 * iw + h3 * wxu, r13 = h3 * iw + h4 * wxu;
            float iy = 1.f - wy;
            dv[0] = r00 * iy + r10 * wy; dv[1] = r01 * iy + r11 * wy;
            dv[2] = r02 * iy + r12 * wy; dv[3] = r03 * iy + r13 * wy;
        }
        float pyv = pychain(ytrk_c);
        int cy0 = (int)floorf(pyv);
        int cy1 = min(cy0 + 1, SRC_H - 1);
        float cwy = pyv - (float)cy0;
        float px1 = pxchain((t0f + 1.f) * SCALE_X);
        float px2 = pxchain((t0f + 2.f) * SCALE_X);
        float px3 = pxchain((t0f + 3.f) * SCALE_X);
        int o1 = (int)floorf(px1) - CS;
        int o2 = (int)floorf(px2) - CS;
        int o3 = (int)floorf(px3) - CS;
        bool c1 = (o1 == 2), c2 = (o2 == 3), c3 = (o3 == 4);
        float w0x = px0 - (float)CS;
        float w1x = px1 - (float)(CS + o1);
        float w2x = px2 - (float)(CS + o2);
        float w3x = px3 - (float)(CS + o3);
        int rr0 = cy0 * SRC_W + CS, rr1 = cy1 * SRC_W + CS;
        float icy = 1.f - cwy;
        {
            f32x4 ra = vrow(vt + rr0, c1, c2, c3, w0x, w1x, w2x, w3x);
            f32x4 rb = vrow(vt + rr1, c1, c2, c3, w0x, w1x, w2x, w3x);
            f32x4 cc = ra * icy + rb * cwy;
            col0[0] = cc.x; col0[1] = cc.y; col0[2] = cc.z; col0[3] = cc.w;
        }
        {
            f32x4 ra = vrow(vt + PLANE + rr0, c1, c2, c3, w0x, w1x, w2x, w3x);
            f32x4 rb = vrow(vt + PLANE + rr1, c1, c2, c3, w0x, w1x, w2x, w3x);
            f32x4 cc = ra * icy + rb * cwy;
            col1[0] = cc.x; col1[1] = cc.y; col1[2] = cc.z; col1[3] = cc.w;
        }
        {
            f32x4 ra = vrow(vt + 2 * PLANE + rr0, c1, c2, c3, w0x, w1x, w2x, w3x);
            f32x4 rb = vrow(vt + 2 * PLANE + rr1, c1, c2, c3, w0x, w1x, w2x, w3x);
            f32x4 cc = ra * icy + rb * cwy;
            col2[0] = cc.x; col2[1] = cc.y; col2[2] = cc.z; col2[3] = cc.w;
        }
#pragma unroll
        for (int k = 0; k < 4; ++k) {
            float xtrk = (t0f + (float)k) * SCALE_X;
            xt[k] = xtrk; yt[k] = ytrk_c;
            float z = 3.0f * __sinf(0.05f * (float)(x0 + k + y)) + fmt;
            vv[k] = (z > 1.38629436f) ? 1.f : 0.f;
            X4[k] = (xtrk - 320.f) / 640.f;
            Y4[k] = (ytrk_c - 240.f) / 640.f;
        }
    } else {
#pragma unroll
        for (int k = 0; k < 4; ++k) {
            int x = x0 + k;
            bool covered = (x < 510);
            float xtrk = 0.f, ytrk = 0.f, dval = 0.f, visv = 0.f;
            if (covered) {
                float txv = fminf(fmaxf((float)x + tdx, 0.f), 511.f);
                int xi0 = (int)floorf(txv);
                int xi1 = min(xi0 + 1, RES_W - 1);
                float wx = txv - (float)xi0;
                int sx0 = xi0 + (xi0 >> 2);
                int sx1 = xi1 + (xi1 >> 2);
                float d00 = dep[dro0 + sx0];
                float d01 = dep[dro0 + sx1];
                float d10 = dep[dro1 + sx0];
                float d11 = dep[dro1 + sx1];
                dval = d00 * ((1.f - wx) * (1.f - wy)) + d01 * (wx * (1.f - wy))
                     + d10 * ((1.f - wx) * wy) + d11 * (wx * wy);
                float z = 3.0f * __sinf(0.05f * (float)(x + y)) + fmt;
                visv = (z > 1.38629436f) ? 1.f : 0.f;
                xtrk = txv * SCALE_X;
                ytrk = ytrk_c;
            }
            xt[k] = xtrk; yt[k] = ytrk; dv[k] = dval; vv[k] = visv;
            X4[k] = (xtrk - 320.f) / 640.f;
            Y4[k] = (ytrk - 240.f) / 640.f;

            float px = pxchain(xtrk);
            float py = pychain(ytrk);
            int cx0 = (int)floorf(px); int cx1 = min(cx0 + 1, SRC_W - 1); float cwx = px - (float)cx0;
            int cy0 = (int)floorf(py); int cy1 = min(cy0 + 1, SRC_H - 1); float cwy = py - (float)cy0;
            float w00 = (1.f - cwx) * (1.f - cwy), w01 = cwx * (1.f - cwy);
            float w10 = (1.f - cwx) * cwy,         w11 = cwx * cwy;
            int r0 = cy0 * SRC_W, r1 = cy1 * SRC_W;
            const float* vc = vt;
            col0[k] = vc[r0 + cx0] * w00 + vc[r0 + cx1] * w01 + vc[r1 + cx0] * w10 + vc[r1 + cx1] * w11;
            vc += PLANE;
            col1[k] = vc[r0 + cx0] * w00 + vc[r0 + cx1] * w01 + vc[r1 + cx0] * w10 + vc[r1 + cx1] * w11;
            vc += PLANE;
            col2[k] = vc[r0 + cx0] * w00 + vc[r0 + cx1] * w01 + vc[r1 + cx0] * w10 + vc[r1 + cx1] * w11;
        }
    }

    size_t tb_blk = (size_t)t * NPIX + (size_t)blk * 1024;
    size_t tb0 = tb_blk + (size_t)lp0;

    __builtin_nontemporal_store((f32x4){dv[0], dv[1], dv[2], dv[3]},
                                (f32x4*)(out + O_Z + tb0));
    __builtin_nontemporal_store((f32x4){vv[0], vv[1], vv[2], vv[3]},
                                (f32x4*)(out + O_VIS + tb0));
    {
        f32x4* oxy = (f32x4*)(out + O_XY + tb0 * 2);
        __builtin_nontemporal_store((f32x4){xt[0], yt[0], xt[1], yt[1]}, oxy);
        __builtin_nontemporal_store((f32x4){xt[2], yt[2], xt[3], yt[3]}, oxy + 1);
    }
    if ((y & 3) == 0) {
        int ns = (y >> 2) * 128 + (x0 >> 2);
        size_t sb = (size_t)t * (96 * 128) + (size_t)ns;
        __builtin_nontemporal_store((f32x2){xt[0], yt[0]},
                                    (f32x2*)(out + O_SPARSE + sb * 2));
    }

    f32x4* ls4 = (f32x4*)ls;
#pragma unroll
    for (int h = 0; h < 2; ++h) {
        __syncthreads();
        if ((tid >> 7) == h) {
            int lt = tid & 127;
            ls4[0 * 128 + lt] = (f32x4){X4[0], X4[1], X4[2], X4[3]};
            ls4[1 * 128 + lt] = (f32x4){Y4[0], Y4[1], Y4[2], Y4[3]};
            ls4[2 * 128 + lt] = (f32x4){dv[0], dv[1], dv[2], dv[3]};
            ls4[3 * 128 + lt] = (f32x4){col0[0], col0[1], col0[2], col0[3]};
            ls4[4 * 128 + lt] = (f32x4){col1[0], col1[1], col1[2], col1[3]};
            ls4[5 * 128 + lt] = (f32x4){col2[0], col2[1], col2[2], col2[3]};
            ls4[6 * 128 + lt] = (f32x4){vv[0], vv[1], vv[2], vv[3]};
        }
        __syncthreads();
        f32x4* tr4 = (f32x4*)(out + O_TRAJ + (tb_blk + (size_t)h * 512) * 7);
#pragma unroll
        for (int s = 0; s < 4; ++s) {
            unsigned m = (unsigned)(s * 256 + tid);
            if (s == 3 && tid >= 128) break;
            unsigned e = 4u * m;
            unsigned p0 = (e + 0u) / 7u, c0 = (e + 0u) - p0 * 7u;
            unsigned p1 = (e + 1u) / 7u, c1 = (e + 1u) - p1 * 7u;
            unsigned p2 = (e + 2u) / 7u, c2 = (e + 2u) - p2 * 7u;
            unsigned p3 = (e + 3u) / 7u, c3 = (e + 3u) - p3 * 7u;
            f32x4 w = {ls[c0 * 512 + p0], ls[c1 * 512 + p1],
                       ls[c2 * 512 + p2], ls[c3 * 512 + p3]};
            __builtin_nontemporal_store(w, tr4 + m);
        }
    }
}

/* ---- fused kernel: per-frame software barrier, no grid sync ---- */

__global__ __launch_bounds__(256, 4) void fused_kernel(
        const float* __restrict__ video, const float* __restrict__ depth,
        double* __restrict__ part, int* __restrict__ cnt,
        float* __restrict__ out) {
    __shared__ float axs[640];
    __shared__ float ays[16];
    __shared__ double sh[256];
    __shared__ float ls[3584];
    __shared__ float featS[3];
    __shared__ float dspS[3];
    __shared__ int flagS;

    int tid = threadIdx.x;
    int b = blockIdx.x;
    int g = b & 15;          /* frame; all 64 blocks of a frame share b%8 -> one XCD */
    int j = b >> 4;          /* 0..63 within frame group */

    for (int xs = tid; xs < SRC_W; xs += 256) axs[xs] = ax_weight(xs);
    if (tid == 0) flagS = 0;

    /* feat phase: 90 units per frame over 64 blocks (26 blocks x2 + 38 x1) */
    int u0, nu;
    if (j < 26) { u0 = 2 * j; nu = 2; } else { u0 = j + 26; nu = 1; }
    for (int ui = 0; ui < nu; ++ui) {
        int u = u0 + ui;
        int pl = (u < 30) ? 0 : (u < 60 ? 1 : 2);
        int ch = u - pl * 30;
        if (tid < 16) ays[tid] = ay_weight(ch * 16 + tid);
        __syncthreads();
        double r = feat_unit(video, axs, ays, 3 * g + pl, ch, tid, sh);
        if (tid == 0) part[(3 * g + pl) * NCH + ch] = r;
        __syncthreads();
    }
    __threadfence();

    /* publish + spin on this frame's counter (bounded; fallback recompute) */
    if (tid == 0) {
        __hip_atomic_fetch_add(&cnt[g], nu, __ATOMIC_RELEASE, __HIP_MEMORY_SCOPE_AGENT);
        int iters = 0;
        while (__hip_atomic_load(&cnt[g], __ATOMIC_ACQUIRE, __HIP_MEMORY_SCOPE_AGENT) < 90) {
            __builtin_amdgcn_s_sleep(2);
            if (++iters > 1000000) { flagS = 1; break; }
        }
    }
    __syncthreads();

    if (flagS) {
        /* safety net: recompute all 90 units of frame g locally (bit-identical) */
        for (int c = 0; c < 3; ++c) {
            double a = 0.0;
            for (int k = 0; k < NCH; ++k) {
                if (tid < 16) ays[tid] = ay_weight(k * 16 + tid);
                __syncthreads();
                double r = feat_unit(video, axs, ays, 3 * g + c, k, tid, sh);
                if (tid == 0) a += r;
                __syncthreads();
            }
            if (tid == 0) featS[c] = (float)a;
        }
    } else {
        if (tid < 3) {
            double s = 0.0;
            const double* pp = part + (3 * g + tid) * NCH;
            for (int k = 0; k < NCH; ++k) s += pp[k];
            featS[tid] = (float)s;
        }
    }
    __syncthreads();
    if (tid == 0) {
        float f0 = featS[0], f1 = featS[1], f2 = featS[2];
        dspS[0] = tanhf(f0) * 2.0f;
        dspS[1] = tanhf(f1) * 2.0f;
        dspS[2] = ((f0 + f1) + f2) / 3.0f;
    }
    __syncthreads();
    float dx = dspS[0], dy = dspS[1], fmt = dspS[2];

    /* tile phase: 3 tiles of frame g per block (192 = 3 * 64) */
    for (int s3 = 0; s3 < 3; ++s3) {
        int blk = j * 3 + s3;
        process_tile(video, depth, dx, dy, fmt, g, blk, tid, ls, out);
    }
}

extern "C" void kernel_launch(void* const* d_in, const int* in_sizes, int n_in,
                              void* d_out, int out_size, void* d_ws, size_t ws_size,
                              hipStream_t stream) {
    const float* video = (const float*)d_in[0];
    const float* depth = (const float*)d_in[1];
    float* out = (float*)d_out;

    double* part = (double*)d_ws;                       /* 1440 doubles = 11520 B */
    int* cnt = (int*)((char*)d_ws + 11520);             /* 16 ints */

    hipMemsetAsync(cnt, 0, 16 * sizeof(int), stream);   /* reset barrier each call */
    fused_kernel<<<1024, 256, 0, stream>>>(video, depth, part, cnt, out);
}

// Round 10
// 54.331 us; speedup vs baseline: 4.3950x; 4.3950x over previous
//
#include <hip/hip_runtime.h>
#include <math.h>

#define SRC_H 480
#define SRC_W 640
#define RES_H 384
#define RES_W 512
#define NT 16
#define NPIX (RES_H * RES_W)        /* 196608 */
#define PLANE (SRC_H * SRC_W)       /* 307200 */
#define NCH 30                      /* chunks per plane in feat pass */
#define NTILES (NT * 192)           /* 3072 */
#define SCALE_X (639.0f / 511.0f)
#define SCALE_Y (479.0f / 383.0f)

typedef float f32x4 __attribute__((ext_vector_type(4)));
typedef float f32x2 __attribute__((ext_vector_type(2)));

/* output layout (floats, concatenated in return order) */
#define O_SPARSE 0
#define N_SPARSE (NT * 96 * 128 * 2)            /* 393216 */
#define O_XY (O_SPARSE + N_SPARSE)
#define N_XY (NT * NPIX * 2)
#define O_Z (O_XY + N_XY)
#define N_Z (NT * NPIX)
#define O_VIS (O_Z + N_Z)
#define O_TRAJ (O_VIS + N_Z)

/* ---- helpers ---- */

__device__ inline f32x4 ld4u(const float* p) {   /* unaligned 16B load */
    f32x4 v; __builtin_memcpy(&v, p, 16); return v;
}

__device__ inline float ay_weight(int i) {
    const float s = 479.0f / 383.0f;
    float acc = 0.f;
    int lo = (int)floorf((float)(i - 1) / s) - 2; if (lo < 0) lo = 0;
    int hi = (int)ceilf((float)(i + 1) / s) + 2; if (hi > RES_H - 1) hi = RES_H - 1;
    for (int oy = lo; oy <= hi; ++oy) {
        float ys = (float)oy * s;
        int y0 = (int)floorf(ys);
        float wy = ys - (float)y0;
        int y1 = min(y0 + 1, SRC_H - 1);
        if (y0 == i) acc += (1.f - wy);
        if (y1 == i) acc += wy;
    }
    return acc * (1.0f / RES_H);
}

__device__ inline float ax_weight(int xs) {
    const float s2 = 639.0f / 511.0f;
    float acc = 0.f;
    int lo = (int)floorf((float)(xs - 1) / s2) - 2; if (lo < 0) lo = 0;
    int hi = (int)ceilf((float)(xs + 1) / s2) + 2; if (hi > RES_W - 1) hi = RES_W - 1;
    for (int ox = lo; ox <= hi; ++ox) {
        float xv = (float)ox * s2;
        int x0 = (int)floorf(xv);
        float wx = xv - (float)x0;
        int x1 = min(x0 + 1, SRC_W - 1);
        if (x0 == xs) acc += (1.f - wx);
        if (x1 == xs) acc += wx;
    }
    return acc * (1.0f / RES_W);
}

__device__ inline float pxchain(float v) {
    float a = v / 640.f; float b = 2.f * (a - 0.5f); float c = b + 1.f;
    float p = (c * 0.5f) * 639.f;
    return fminf(fmaxf(p, 0.f), 639.f);
}
__device__ inline float pychain(float v) {
    float a = v / 480.f; float b = 2.f * (a - 0.5f); float c = b + 1.f;
    float p = (c * 0.5f) * 479.f;
    return fminf(fmaxf(p, 0.f), 479.f);
}

/* 4-pixel bilinear row-lerp from a 6-float window with binary offset selects */
__device__ inline f32x4 vrow(const float* rp, bool c1, bool c2, bool c3,
                             float w0, float w1, float w2, float w3) {
    f32x4 A = ld4u(rp), B = ld4u(rp + 4);
    float q0 = A.x, q1 = A.y, q2 = A.z, q3 = A.w, q4 = B.x, q5 = B.y;
    float u0 = q0,            t0 = q1;
    float u1 = c1 ? q2 : q1,  t1 = c1 ? q3 : q2;
    float u2 = c2 ? q3 : q2,  t2 = c2 ? q4 : q3;
    float u3 = c3 ? q4 : q3,  t3 = c3 ? q5 : q4;
    return (f32x4){u0 * (1.f - w0) + t0 * w0, u1 * (1.f - w1) + t1 * w1,
                   u2 * (1.f - w2) + t2 * w2, u3 * (1.f - w3) + t3 * w3};
}

/* ---- kernel 1: feat partial reductions ---- */

__global__ __launch_bounds__(256) void feat_kernel(
        const float* __restrict__ video, double* __restrict__ part) {
    int chunk = blockIdx.x;
    int plane = blockIdx.y;
    int tid = threadIdx.x;
    __shared__ float axs[640];
    __shared__ float ays[16];
    for (int xs = tid; xs < SRC_W; xs += 256) axs[xs] = ax_weight(xs);
    if (tid < 16) ays[tid] = ay_weight(chunk * 16 + tid);
    __syncthreads();

    const f32x4* v = (const f32x4*)(video + (size_t)plane * PLANE + (size_t)chunk * 10240);
    double s = 0.0;
#pragma unroll
    for (int it = 0; it < 10; ++it) {
        int idx = it * 256 + tid;
        f32x4 q = v[idx];
        int row = idx / 160;
        int xq = (idx - row * 160) * 4;
        float w = ays[row];
        s += (double)(w * axs[xq + 0]) * (double)q.x
           + (double)(w * axs[xq + 1]) * (double)q.y
           + (double)(w * axs[xq + 2]) * (double)q.z
           + (double)(w * axs[xq + 3]) * (double)q.w;
    }
    __shared__ double sh[256];
    sh[tid] = s;
    __syncthreads();
    for (int off = 128; off > 0; off >>= 1) {
        if (tid < off) sh[tid] += sh[tid + off];
        __syncthreads();
    }
    if (tid == 0) part[plane * NCH + chunk] = sh[0];
}

/* ---- kernel 2: per-block finalize + one output tile ---- */

__global__ __launch_bounds__(256) void main_kernel(
        const float* __restrict__ video, const float* __restrict__ depth,
        const double* __restrict__ part, float* __restrict__ out) {
    __shared__ float ls[3584];          /* 14 KB: half-tile traj staging */
    __shared__ float featS[48];
    __shared__ float dispS[32];
    __shared__ float fmS[16];

    int tid = threadIdx.x;
    int t = blockIdx.x / 192;
    int blk = blockIdx.x - t * 192;

    /* redundant finalize: bit-identical order across blocks */
    if (tid < 48) {
        double s = 0.0;
        for (int k = 0; k < NCH; ++k) s += part[tid * NCH + k];
        featS[tid] = (float)s;
    }
    __syncthreads();
    if (tid < NT) {
        float f0 = featS[tid * 3 + 0];
        float f1 = featS[tid * 3 + 1];
        float f2 = featS[tid * 3 + 2];
        dispS[2 * tid + 0] = tanhf(f0) * 2.0f;
        dispS[2 * tid + 1] = tanhf(f1) * 2.0f;
        fmS[tid] = ((f0 + f1) + f2) / 3.0f;
    }
    __syncthreads();

    float dx = dispS[2 * t + 0];
    float dy = dispS[2 * t + 1];
    float fmt = fmS[t];

    int lp0 = tid * 4;
    int y = blk * 2 + (tid >> 7);
    int x0 = (tid & 127) << 2;
    float tf = (float)t;

    float tyv = fminf(fmaxf((float)y + tf * dy, 0.f), 383.f);
    int y0 = (int)floorf(tyv);
    int y1 = min(y0 + 1, RES_H - 1);
    float wy = tyv - (float)y0;
    const float* dep = depth + (size_t)t * PLANE;
    int dro0 = (y0 + (y0 >> 2)) * SRC_W;
    int dro1 = (y1 + (y1 >> 2)) * SRC_W;
    float ytrk_c = tyv * SCALE_Y;

    const float* vt = video + (size_t)t * 3 * PLANE;

    float xt[4], yt[4], dv[4], vv[4], X4[4], Y4[4], col0[4], col1[4], col2[4];

    /* ---- vector fast path ---- */
    float tdx = tf * dx;
    float t0f = (float)x0 + tdx;
    int X = (int)floorf(t0f);
    float xtrk0 = t0f * SCALE_X;
    float px0 = pxchain(xtrk0);
    int CS = (int)floorf(px0);
    bool vecok = (x0 <= 504) && (t0f >= 0.f) && (t0f + 3.f <= 511.f)
              && (X <= 506) && (CS <= 632);

    if (vecok) {
        float wxu = t0f - (float)X;        /* == wx for all 4 px (exact) */
        int s0 = X + (X >> 2);
        int bq = X & 3;
        bool d1 = (bq == 3), d2 = (bq >= 2), d3 = (bq >= 1);
        {
            f32x4 Da = ld4u(dep + dro0 + s0), Db = ld4u(dep + dro0 + s0 + 4);
            f32x4 Ea = ld4u(dep + dro1 + s0), Eb = ld4u(dep + dro1 + s0 + 4);
            float a0 = Da.x, a1 = Da.y, a2 = Da.z, a3 = Da.w, a4 = Db.x, a5 = Db.y;
            float v0 = a0, v1 = d1 ? a2 : a1, v2 = d2 ? a3 : a2, v3 = d3 ? a4 : a3, v4 = a5;
            float g0 = Ea.x, g1 = Ea.y, g2 = Ea.z, g3 = Ea.w, g4 = Eb.x, g5 = Eb.y;
            float h0 = g0, h1 = d1 ? g2 : g1, h2 = d2 ? g3 : g2, h3 = d3 ? g4 : g3, h4 = g5;
            float iw = 1.f - wxu;
            float r00 = v0 * iw + v1 * wxu, r01 = v1 * iw + v2 * wxu;
            float r02 = v2 * iw + v3 * wxu, r03 = v3 * iw + v4 * wxu;
            float r10 = h0 * iw + h1 * wxu, r11 = h1 * iw + h2 * wxu;
            float r12 = h2 * iw + h3 * wxu, r13 = h3 * iw + h4 * wxu;
            float iy = 1.f - wy;
            dv[0] = r00 * iy + r10 * wy; dv[1] = r01 * iy + r11 * wy;
            dv[2] = r02 * iy + r12 * wy; dv[3] = r03 * iy + r13 * wy;
        }
        float pyv = pychain(ytrk_c);
        int cy0 = (int)floorf(pyv);
        int cy1 = min(cy0 + 1, SRC_H - 1);
        float cwy = pyv - (float)cy0;
        float px1 = pxchain((t0f + 1.f) * SCALE_X);
        float px2 = pxchain((t0f + 2.f) * SCALE_X);
        float px3 = pxchain((t0f + 3.f) * SCALE_X);
        int o1 = (int)floorf(px1) - CS;
        int o2 = (int)floorf(px2) - CS;
        int o3 = (int)floorf(px3) - CS;
        bool c1 = (o1 == 2), c2 = (o2 == 3), c3 = (o3 == 4);
        float w0x = px0 - (float)CS;
        float w1x = px1 - (float)(CS + o1);
        float w2x = px2 - (float)(CS + o2);
        float w3x = px3 - (float)(CS + o3);
        int rr0 = cy0 * SRC_W + CS, rr1 = cy1 * SRC_W + CS;
        float icy = 1.f - cwy;
        {
            f32x4 ra = vrow(vt + rr0, c1, c2, c3, w0x, w1x, w2x, w3x);
            f32x4 rb = vrow(vt + rr1, c1, c2, c3, w0x, w1x, w2x, w3x);
            f32x4 cc = ra * icy + rb * cwy;
            col0[0] = cc.x; col0[1] = cc.y; col0[2] = cc.z; col0[3] = cc.w;
        }
        {
            f32x4 ra = vrow(vt + PLANE + rr0, c1, c2, c3, w0x, w1x, w2x, w3x);
            f32x4 rb = vrow(vt + PLANE + rr1, c1, c2, c3, w0x, w1x, w2x, w3x);
            f32x4 cc = ra * icy + rb * cwy;
            col1[0] = cc.x; col1[1] = cc.y; col1[2] = cc.z; col1[3] = cc.w;
        }
        {
            f32x4 ra = vrow(vt + 2 * PLANE + rr0, c1, c2, c3, w0x, w1x, w2x, w3x);
            f32x4 rb = vrow(vt + 2 * PLANE + rr1, c1, c2, c3, w0x, w1x, w2x, w3x);
            f32x4 cc = ra * icy + rb * cwy;
            col2[0] = cc.x; col2[1] = cc.y; col2[2] = cc.z; col2[3] = cc.w;
        }
#pragma unroll
        for (int k = 0; k < 4; ++k) {
            float xtrk = (t0f + (float)k) * SCALE_X;
            xt[k] = xtrk; yt[k] = ytrk_c;
            float z = 3.0f * __sinf(0.05f * (float)(x0 + k + y)) + fmt;
            vv[k] = (z > 1.38629436f) ? 1.f : 0.f;
            X4[k] = (xtrk - 320.f) / 640.f;
            Y4[k] = (ytrk_c - 240.f) / 640.f;
        }
    } else {
        /* ---- scalar fallback ---- */
#pragma unroll
        for (int k = 0; k < 4; ++k) {
            int x = x0 + k;
            bool covered = (x < 510);
            float xtrk = 0.f, ytrk = 0.f, dval = 0.f, visv = 0.f;
            if (covered) {
                float txv = fminf(fmaxf((float)x + tdx, 0.f), 511.f);
                int xi0 = (int)floorf(txv);
                int xi1 = min(xi0 + 1, RES_W - 1);
                float wx = txv - (float)xi0;
                int sx0 = xi0 + (xi0 >> 2);
                int sx1 = xi1 + (xi1 >> 2);
                float d00 = dep[dro0 + sx0];
                float d01 = dep[dro0 + sx1];
                float d10 = dep[dro1 + sx0];
                float d11 = dep[dro1 + sx1];
                dval = d00 * ((1.f - wx) * (1.f - wy)) + d01 * (wx * (1.f - wy))
                     + d10 * ((1.f - wx) * wy) + d11 * (wx * wy);
                float z = 3.0f * __sinf(0.05f * (float)(x + y)) + fmt;
                visv = (z > 1.38629436f) ? 1.f : 0.f;
                xtrk = txv * SCALE_X;
                ytrk = ytrk_c;
            }
            xt[k] = xtrk; yt[k] = ytrk; dv[k] = dval; vv[k] = visv;
            X4[k] = (xtrk - 320.f) / 640.f;
            Y4[k] = (ytrk - 240.f) / 640.f;

            float px = pxchain(xtrk);
            float py = pychain(ytrk);
            int cx0 = (int)floorf(px); int cx1 = min(cx0 + 1, SRC_W - 1); float cwx = px - (float)cx0;
            int cy0 = (int)floorf(py); int cy1 = min(cy0 + 1, SRC_H - 1); float cwy = py - (float)cy0;
            float w00 = (1.f - cwx) * (1.f - cwy), w01 = cwx * (1.f - cwy);
            float w10 = (1.f - cwx) * cwy,         w11 = cwx * cwy;
            int r0 = cy0 * SRC_W, r1 = cy1 * SRC_W;
            const float* vc = vt;
            col0[k] = vc[r0 + cx0] * w00 + vc[r0 + cx1] * w01 + vc[r1 + cx0] * w10 + vc[r1 + cx1] * w11;
            vc += PLANE;
            col1[k] = vc[r0 + cx0] * w00 + vc[r0 + cx1] * w01 + vc[r1 + cx0] * w10 + vc[r1 + cx1] * w11;
            vc += PLANE;
            col2[k] = vc[r0 + cx0] * w00 + vc[r0 + cx1] * w01 + vc[r1 + cx0] * w10 + vc[r1 + cx1] * w11;
        }
    }

    size_t tb_blk = (size_t)t * NPIX + (size_t)blk * 1024;
    size_t tb0 = tb_blk + (size_t)lp0;

    /* direct nt stores: z, vis (16B lane-linear) */
    __builtin_nontemporal_store((f32x4){dv[0], dv[1], dv[2], dv[3]},
                                (f32x4*)(out + O_Z + tb0));
    __builtin_nontemporal_store((f32x4){vv[0], vv[1], vv[2], vv[3]},
                                (f32x4*)(out + O_VIS + tb0));
    /* xy direct: 2 x f32x4 at 32B lane stride */
    {
        f32x4* oxy = (f32x4*)(out + O_XY + tb0 * 2);
        __builtin_nontemporal_store((f32x4){xt[0], yt[0], xt[1], yt[1]}, oxy);
        __builtin_nontemporal_store((f32x4){xt[2], yt[2], xt[3], yt[3]}, oxy + 1);
    }
    if ((y & 3) == 0) {
        int ns = (y >> 2) * 128 + (x0 >> 2);
        size_t sb = (size_t)t * (96 * 128) + (size_t)ns;
        __builtin_nontemporal_store((f32x2){xt[0], yt[0]},
                                    (f32x2*)(out + O_SPARSE + sb * 2));
    }

    /* traj via two half-tile LDS transposes (512 px each, 3584 floats) */
    f32x4* ls4 = (f32x4*)ls;
#pragma unroll
    for (int h = 0; h < 2; ++h) {
        __syncthreads();
        if ((tid >> 7) == h) {
            int lt = tid & 127;
            ls4[0 * 128 + lt] = (f32x4){X4[0], X4[1], X4[2], X4[3]};
            ls4[1 * 128 + lt] = (f32x4){Y4[0], Y4[1], Y4[2], Y4[3]};
            ls4[2 * 128 + lt] = (f32x4){dv[0], dv[1], dv[2], dv[3]};
            ls4[3 * 128 + lt] = (f32x4){col0[0], col0[1], col0[2], col0[3]};
            ls4[4 * 128 + lt] = (f32x4){col1[0], col1[1], col1[2], col1[3]};
            ls4[5 * 128 + lt] = (f32x4){col2[0], col2[1], col2[2], col2[3]};
            ls4[6 * 128 + lt] = (f32x4){vv[0], vv[1], vv[2], vv[3]};
        }
        __syncthreads();
        f32x4* tr4 = (f32x4*)(out + O_TRAJ + (tb_blk + (size_t)h * 512) * 7);
#pragma unroll
        for (int s = 0; s < 4; ++s) {
            unsigned m = (unsigned)(s * 256 + tid);
            if (s == 3 && tid >= 128) break;
            unsigned e = 4u * m;
            unsigned p0 = (e + 0u) / 7u, c0 = (e + 0u) - p0 * 7u;
            unsigned p1 = (e + 1u) / 7u, c1 = (e + 1u) - p1 * 7u;
            unsigned p2 = (e + 2u) / 7u, c2 = (e + 2u) - p2 * 7u;
            unsigned p3 = (e + 3u) / 7u, c3 = (e + 3u) - p3 * 7u;
            f32x4 w = {ls[c0 * 512 + p0], ls[c1 * 512 + p1],
                       ls[c2 * 512 + p2], ls[c3 * 512 + p3]};
            __builtin_nontemporal_store(w, tr4 + m);
        }
    }
}

extern "C" void kernel_launch(void* const* d_in, const int* in_sizes, int n_in,
                              void* d_out, int out_size, void* d_ws, size_t ws_size,
                              hipStream_t stream) {
    const float* video = (const float*)d_in[0];
    const float* depth = (const float*)d_in[1];
    float* out = (float*)d_out;

    double* part = (double*)d_ws;            /* 1440 doubles = 11520 B */

    feat_kernel<<<dim3(NCH, NT * 3), 256, 0, stream>>>(video, part);
    main_kernel<<<NTILES, 256, 0, stream>>>(video, depth, part, out);
}